// Round 2
// baseline (245.445 us; speedup 1.0000x reference)
//
#include <hip/hip_runtime.h>

// B=8, Cin=Cout=32, H=W=256, K=5. Adaptive bins: start (k*256)/5 = {0,51,102,153,204},
// all length 52 (bins overlap by 1 row/col).
// Pooling is linear: filt_raw[b,o,k,l] = sum_i W[o,i]*xpool_raw[b,i,k,l] + 2704*bias[o]
// so we pool x (tiny) instead of feat, and the 1x1 conv is a pure streaming channel mix.
// Launch order conv -> pool -> dw: pool reads L3-warm x, dw reads L3-warm feat.

#define CIN 32
#define COUT 32
#define HW 256
#define PLANE (HW * HW)
#define BATCH 8
#define KF 5
#define BIN 52

// ---------------- K0: pure 1x1 conv (channel mix), register-tiled ----------------
// Grid 1024 = b*128 + pg*2 + oh. Block 256 threads.
// Thread: 4 adjacent pixels (one float4) x 8 outputs per pass, 2 passes (16 o per block).
// 32 accumulator VGPRs -> no spill (Round-1 version kept 64 live accs and spilled:
// VGPR=60 < 64 live, 5.4x VALU amplification, 64 us).
__global__ __launch_bounds__(256, 4) void conv_kernel(const float* __restrict__ x,
                                                      const float* __restrict__ Wm,
                                                      const float* __restrict__ bias,
                                                      float* __restrict__ feat) {
    int blk = blockIdx.x;
    int oh  = blk & 1;             // o-half: outputs oh*16 .. oh*16+15
    int pg  = (blk >> 1) & 63;     // pixel group: 1024 px = 4 rows
    int b   = blk >> 7;
    int t   = threadIdx.x;

    size_t pixbase = (size_t)pg * 1024 + (size_t)t * 4;
    const float* xb = x + (size_t)b * CIN * PLANE + pixbase;
    float*       fb = feat + (size_t)b * COUT * PLANE + pixbase;

#pragma unroll
    for (int pass = 0; pass < 2; ++pass) {
        int o0 = oh * 16 + pass * 8;
        float4 acc[8];
#pragma unroll
        for (int u = 0; u < 8; ++u) {
            float bv = bias[o0 + u];
            acc[u].x = bv; acc[u].y = bv; acc[u].z = bv; acc[u].w = bv;
        }
#pragma unroll
        for (int i = 0; i < CIN; ++i) {
            float4 xv = *(const float4*)(xb + (size_t)i * PLANE);   // 1KB per wave-instr
#pragma unroll
            for (int u = 0; u < 8; ++u) {
                float w = Wm[(o0 + u) * CIN + i];   // thread-uniform -> s_load / K$
                acc[u].x += w * xv.x;
                acc[u].y += w * xv.y;
                acc[u].z += w * xv.z;
                acc[u].w += w * xv.w;
            }
        }
#pragma unroll
        for (int u = 0; u < 8; ++u)
            *(float4*)(fb + (size_t)(o0 + u) * PLANE) = acc[u];
    }
}

// ---------------- K1: pool x -> xpool_raw[b][i][25] (raw 52x52 bin sums) ----------------
// Grid 2048 = (b*32+i)*8 + strip ; 256 threads = 256 cols; strip = 32 rows.
__global__ __launch_bounds__(256) void pool_x_kernel(const float* __restrict__ x,
                                                     float* __restrict__ xpool) {
    int blk   = blockIdx.x;
    int s     = blk & 7;           // row strip 0..7
    int plane = blk >> 3;          // b*32+i, 0..255
    int t     = threadIdx.x;
    int gy0   = s * 32;

    const float* xp = x + (size_t)plane * PLANE + (size_t)gy0 * HW + t;
    float acc[KF] = {0.f, 0.f, 0.f, 0.f, 0.f};
#pragma unroll
    for (int r = 0; r < 32; ++r) {
        float v  = xp[(size_t)r * HW];
        int   gy = gy0 + r;
#pragma unroll
        for (int k = 0; k < KF; ++k) {            // row-bin membership (bins overlap by 1)
            const int sk = (k * HW) / KF;
            if (gy >= sk && gy < sk + BIN) acc[k] += v;
        }
    }

    __shared__ float lds[KF][HW + 1];
#pragma unroll
    for (int k = 0; k < KF; ++k) lds[k][t] = acc[k];
    __syncthreads();

    if (t < KF * KF) {                            // 25 workers: (row-bin kk, col-bin ll)
        int kk = t / KF, ll = t - kk * KF;
        int sl = (ll * HW) / KF;
        float ssum = 0.f;
#pragma unroll 4
        for (int w = 0; w < BIN; ++w) ssum += lds[kk][sl + w];
        atomicAdd(&xpool[plane * 25 + t], ssum);  // 2048*25 atomics total - negligible
    }
}

// ---------------- K2: depthwise 5x5, 32-row x 256-col strips, register sliding window ----
// filt computed in prologue from xpool_raw (linearity of pooling).
#define LROW 264   // LDS row stride (floats); interior col x at [lr*LROW + 4 + x]
__global__ __launch_bounds__(256) void dwconv_kernel(const float* __restrict__ feat,
                                                     const float* __restrict__ xpool,
                                                     const float* __restrict__ Wm,
                                                     const float* __restrict__ bias,
                                                     float* __restrict__ out) {
    int bo    = blockIdx.y;            // 0..255  (b*32+o)
    int b     = bo >> 5;
    int o     = bo & 31;
    int strip = blockIdx.x;            // 0..7
    int gy0   = strip * 32;
    int t     = threadIdx.x;

    __shared__ __align__(16) float s[36 * LROW];
    __shared__ float sfilt[25];

    // filt[k][l] = (sum_i W[o,i]*xpool_raw[b,i,k,l] + 2704*bias[o]) / 2704
    if (t < 25) {
        float acc = bias[o] * 2704.0f;
        const float* xp = xpool + (size_t)b * CIN * 25 + t;
#pragma unroll
        for (int i = 0; i < CIN; ++i) acc += Wm[o * CIN + i] * xp[i * 25];
        sfilt[t] = acc * (1.0f / 2704.0f);
    }
    // zero the 2-col pads (LDS idx 2,3 and 260,261) on each of 36 rows
    if (t < 144) {
        int lr = t >> 2, e = t & 3;
        int ci = (e < 2) ? (2 + e) : (258 + e);
        s[lr * LROW + ci] = 0.f;
    }

    const float* fb = feat + (size_t)bo * PLANE;
#pragma unroll
    for (int j = 0; j < 9; ++j) {          // 36 rows x 64 float4 = 2304 / 256 threads
        int idx = t + 256 * j;
        int lr  = idx >> 6;
        int cx  = (idx & 63) * 4;
        int gy  = gy0 - 2 + lr;
        float4 v = {0.f, 0.f, 0.f, 0.f};
        if ((unsigned)gy < (unsigned)HW) v = *(const float4*)(fb + (size_t)gy * HW + cx);
        *(float4*)(&s[lr * LROW + 4 + cx]) = v;
    }
    __syncthreads();

    float fw[25];
#pragma unroll
    for (int j = 0; j < 25; ++j) fw[j] = sfilt[j];   // LDS broadcast once

    int c = t;   // output column
    float w0[5], w1[5], w2[5], w3[5], w4[5];
#pragma unroll
    for (int j = 0; j < 5; ++j) {
        w0[j] = s[0 * LROW + 2 + c + j];
        w1[j] = s[1 * LROW + 2 + c + j];
        w2[j] = s[2 * LROW + 2 + c + j];
        w3[j] = s[3 * LROW + 2 + c + j];
    }
    float* ob = out + (size_t)bo * PLANE + (size_t)gy0 * HW + c;
#pragma unroll
    for (int r = 0; r < 32; ++r) {
#pragma unroll
        for (int j = 0; j < 5; ++j) w4[j] = s[(r + 4) * LROW + 2 + c + j];
        float acc = 0.f;
#pragma unroll
        for (int j = 0; j < 5; ++j) {
            acc += fw[0 * 5 + j] * w0[j];
            acc += fw[1 * 5 + j] * w1[j];
            acc += fw[2 * 5 + j] * w2[j];
            acc += fw[3 * 5 + j] * w3[j];
            acc += fw[4 * 5 + j] * w4[j];
        }
        ob[(size_t)r * HW] = acc;
#pragma unroll
        for (int j = 0; j < 5; ++j) {      // renamed away under full unroll
            w0[j] = w1[j]; w1[j] = w2[j]; w2[j] = w3[j]; w3[j] = w4[j];
        }
    }
}

extern "C" void kernel_launch(void* const* d_in, const int* in_sizes, int n_in,
                              void* d_out, int out_size, void* d_ws, size_t ws_size,
                              hipStream_t stream) {
    const float* x      = (const float*)d_in[0];
    const float* conv_w = (const float*)d_in[1];
    const float* conv_b = (const float*)d_in[2];
    float* out = (float*)d_out;

    float* feat  = (float*)d_ws;                           // 64 MiB
    float* xpool = feat + (size_t)BATCH * COUT * PLANE;    // 8*32*25 floats (raw x bin sums)

    hipMemsetAsync(xpool, 0, BATCH * CIN * 25 * sizeof(float), stream);
    conv_kernel<<<dim3(1024), dim3(256), 0, stream>>>(x, conv_w, conv_b, feat);
    pool_x_kernel<<<dim3(2048), dim3(256), 0, stream>>>(x, xpool);
    dwconv_kernel<<<dim3(8, BATCH * COUT), dim3(256), 0, stream>>>(feat, xpool, conv_w, conv_b, out);
}

// Round 3
// 165.392 us; speedup vs baseline: 1.4840x; 1.4840x over previous
//
#include <hip/hip_runtime.h>

// B=8, Cin=Cout=32, H=W=256, K=5. Adaptive bins: start (k*256)/5 = {0,51,102,153,204},
// all length 52 (bins overlap by 1 row/col).
// Pooling is linear: filt_raw[b,o,k,l] = sum_i W[o,i]*xpool_raw[b,i,k,l] + 2704*bias[o]
// so we pool x (tiny) instead of feat; the 1x1 conv is a pure streaming channel mix.
// Order conv -> pool -> dw: pool reads L3-warm x, dw reads L3-warm feat.

#define CIN 32
#define COUT 32
#define HW 256
#define PLANE (HW * HW)
#define BATCH 8
#define KF 5
#define BIN 52

// ---------------- K0: pure 1x1 conv (channel mix) ----------------
// Block = one (b,row); thread = one pixel. x read EXACTLY ONCE per block (Round-2
// re-read 4x -> FETCH 219MB, 116us). Thread preloads all 32 x-channel values (32 VGPR),
// then per o: one dot product, store immediately -> 1 live accumulator, no spill.
// Weight row Wm[o][0..31] contiguous -> s_load_dwordx16 pairs on the scalar pipe.
__global__ __launch_bounds__(256) void conv_kernel(const float* __restrict__ x,
                                                   const float* __restrict__ Wm,
                                                   const float* __restrict__ bias,
                                                   float* __restrict__ feat) {
    int blk = blockIdx.x;          // b*256 + row
    int b   = blk >> 8;
    int row = blk & 255;
    int t   = threadIdx.x;

    const float* xb = x + (size_t)b * CIN * PLANE + (size_t)row * HW + t;
    float xv[CIN];
#pragma unroll
    for (int i = 0; i < CIN; ++i) xv[i] = xb[(size_t)i * PLANE];   // 256B/wave, coalesced

    float* fb = feat + (size_t)b * COUT * PLANE + (size_t)row * HW + t;
#pragma unroll
    for (int o = 0; o < COUT; ++o) {
        float acc = bias[o];
#pragma unroll
        for (int i = 0; i < CIN; ++i) acc += Wm[o * CIN + i] * xv[i];  // sgpr weights
        fb[(size_t)o * PLANE] = acc;
    }
}

// ---------------- K1: pool x -> xpool_raw[b][i][25] (raw 52x52 bin sums) ----------------
// Grid 2048 = (b*32+i)*8 + strip ; 256 threads = 256 cols; strip = 32 rows.
__global__ __launch_bounds__(256) void pool_x_kernel(const float* __restrict__ x,
                                                     float* __restrict__ xpool) {
    int blk   = blockIdx.x;
    int s     = blk & 7;           // row strip 0..7
    int plane = blk >> 3;          // b*32+i, 0..255
    int t     = threadIdx.x;
    int gy0   = s * 32;

    const float* xp = x + (size_t)plane * PLANE + (size_t)gy0 * HW + t;
    float acc[KF] = {0.f, 0.f, 0.f, 0.f, 0.f};
#pragma unroll
    for (int r = 0; r < 32; ++r) {
        float v  = xp[(size_t)r * HW];
        int   gy = gy0 + r;
#pragma unroll
        for (int k = 0; k < KF; ++k) {            // row-bin membership (bins overlap by 1)
            const int sk = (k * HW) / KF;
            if (gy >= sk && gy < sk + BIN) acc[k] += v;
        }
    }

    __shared__ float lds[KF][HW + 1];
#pragma unroll
    for (int k = 0; k < KF; ++k) lds[k][t] = acc[k];
    __syncthreads();

    if (t < KF * KF) {                            // 25 workers: (row-bin kk, col-bin ll)
        int kk = t / KF, ll = t - kk * KF;
        int sl = (ll * HW) / KF;
        float ssum = 0.f;
#pragma unroll 4
        for (int w = 0; w < BIN; ++w) ssum += lds[kk][sl + w];
        atomicAdd(&xpool[plane * 25 + t], ssum);  // 2048*25 atomics total - negligible
    }
}

// ---------------- K2: depthwise 5x5, 16-row x 256-col strips, register sliding window ----
// 16-row strips: LDS 21KB -> 7 blocks/CU (was 37KB -> 4), so staging of one block
// overlaps compute of others. filt from xpool_raw in prologue (linearity of pooling).
#define RS 16      // output rows per strip
#define LROW 264   // LDS row stride (floats); interior col x at [lr*LROW + 4 + x]
__global__ __launch_bounds__(256, 6) void dwconv_kernel(const float* __restrict__ feat,
                                                        const float* __restrict__ xpool,
                                                        const float* __restrict__ Wm,
                                                        const float* __restrict__ bias,
                                                        float* __restrict__ out) {
    int bo    = blockIdx.y;            // 0..255  (b*32+o)
    int b     = bo >> 5;
    int o     = bo & 31;
    int strip = blockIdx.x;            // 0..15
    int gy0   = strip * RS;
    int t     = threadIdx.x;

    __shared__ __align__(16) float s[(RS + 4) * LROW];
    __shared__ float sfilt[25];

    // filt[k][l] = (sum_i W[o,i]*xpool_raw[b,i,k,l] + 2704*bias[o]) / 2704
    if (t < 25) {
        float acc = bias[o] * 2704.0f;
        const float* xp = xpool + (size_t)b * CIN * 25 + t;
#pragma unroll
        for (int i = 0; i < CIN; ++i) acc += Wm[o * CIN + i] * xp[i * 25];
        sfilt[t] = acc * (1.0f / 2704.0f);
    }
    // zero the 2-col pads (LDS idx 2,3 and 260,261) on each of RS+4 rows
    if (t < (RS + 4) * 4) {
        int lr = t >> 2, e = t & 3;
        int ci = (e < 2) ? (2 + e) : (258 + e);
        s[lr * LROW + ci] = 0.f;
    }

    const float* fb = feat + (size_t)bo * PLANE;
#pragma unroll
    for (int j = 0; j < 5; ++j) {          // (RS+4) rows x 64 float4 = 1280 / 256 threads
        int idx = t + 256 * j;
        int lr  = idx >> 6;
        int cx  = (idx & 63) * 4;
        int gy  = gy0 - 2 + lr;
        float4 v = {0.f, 0.f, 0.f, 0.f};
        if ((unsigned)gy < (unsigned)HW) v = *(const float4*)(fb + (size_t)gy * HW + cx);
        *(float4*)(&s[lr * LROW + 4 + cx]) = v;
    }
    __syncthreads();

    float fw[25];
#pragma unroll
    for (int j = 0; j < 25; ++j) fw[j] = sfilt[j];   // LDS broadcast once

    int c = t;   // output column
    float w0[5], w1[5], w2[5], w3[5], w4[5];
#pragma unroll
    for (int j = 0; j < 5; ++j) {
        w0[j] = s[0 * LROW + 2 + c + j];
        w1[j] = s[1 * LROW + 2 + c + j];
        w2[j] = s[2 * LROW + 2 + c + j];
        w3[j] = s[3 * LROW + 2 + c + j];
    }
    float* ob = out + (size_t)bo * PLANE + (size_t)gy0 * HW + c;
#pragma unroll
    for (int r = 0; r < RS; ++r) {
#pragma unroll
        for (int j = 0; j < 5; ++j) w4[j] = s[(r + 4) * LROW + 2 + c + j];
        float acc = 0.f;
#pragma unroll
        for (int j = 0; j < 5; ++j) {
            acc += fw[0 * 5 + j] * w0[j];
            acc += fw[1 * 5 + j] * w1[j];
            acc += fw[2 * 5 + j] * w2[j];
            acc += fw[3 * 5 + j] * w3[j];
            acc += fw[4 * 5 + j] * w4[j];
        }
        ob[(size_t)r * HW] = acc;
#pragma unroll
        for (int j = 0; j < 5; ++j) {      // renamed away under full unroll
            w0[j] = w1[j]; w1[j] = w2[j]; w2[j] = w3[j]; w3[j] = w4[j];
        }
    }
}

extern "C" void kernel_launch(void* const* d_in, const int* in_sizes, int n_in,
                              void* d_out, int out_size, void* d_ws, size_t ws_size,
                              hipStream_t stream) {
    const float* x      = (const float*)d_in[0];
    const float* conv_w = (const float*)d_in[1];
    const float* conv_b = (const float*)d_in[2];
    float* out = (float*)d_out;

    float* feat  = (float*)d_ws;                           // 64 MiB
    float* xpool = feat + (size_t)BATCH * COUT * PLANE;    // 8*32*25 floats (raw x bin sums)

    hipMemsetAsync(xpool, 0, BATCH * CIN * 25 * sizeof(float), stream);
    conv_kernel<<<dim3(BATCH * 256), dim3(256), 0, stream>>>(x, conv_w, conv_b, feat);
    pool_x_kernel<<<dim3(2048), dim3(256), 0, stream>>>(x, xpool);
    dwconv_kernel<<<dim3(HW / RS, BATCH * COUT), dim3(256), 0, stream>>>(feat, xpool, conv_w, conv_b, out);
}

// Round 4
// 164.070 us; speedup vs baseline: 1.4960x; 1.0081x over previous
//
#include <hip/hip_runtime.h>

// B=8, Cin=Cout=32, H=W=256, K=5. Adaptive bins: start (k*256)/5 = {0,51,102,153,204},
// all length 52 (bins overlap by 1 row/col).
// Pooling is linear: filt_raw[b,o,k,l] = sum_i W[o,i]*xpool_raw[b,i,k,l] + 2704*bias[o]
// so we pool x (tiny) instead of feat; the 1x1 conv is a pure streaming channel mix.
// Order conv -> pool -> dw: pool reads L3-warm x, dw reads L3-warm feat.

#define CIN 32
#define COUT 32
#define HW 256
#define PLANE (HW * HW)
#define BATCH 8
#define KF 5
#define BIN 52

// ---------------- K0: pure 1x1 conv (channel mix) ----------------
// Thread = 2 adjacent pixels. Explicit float2 xv[32] (64 VGPR) preloaded ONCE --
// x read exactly once per block; per o: one float2 dot, store immediately (1 live acc).
// __launch_bounds__(256,4) caps VGPR at 128: room for the live set, and stops the
// allocator from shrinking to 24 regs + cache re-reads (Round-3: VGPR=24, 51us,
// VALUBusy 26% -- latency-bound on serialized rematerialized loads).
// Round-2 proved this float-vector structure sustains 3.7+ TB/s when not spilling.
__global__ __launch_bounds__(256, 4) void conv_kernel(const float* __restrict__ x,
                                                      const float* __restrict__ Wm,
                                                      const float* __restrict__ bias,
                                                      float* __restrict__ feat) {
    int blk = blockIdx.x;          // 1024 blocks: b*128 + pg (pg = 512-px group = 2 rows)
    int b   = blk >> 7;
    int pg  = blk & 127;
    int t   = threadIdx.x;

    size_t pix = (size_t)pg * 512 + (size_t)t * 2;
    const float* xb = x + (size_t)b * CIN * PLANE + pix;
    float*       fb = feat + (size_t)b * COUT * PLANE + pix;

    float2 xv[CIN];
#pragma unroll
    for (int i = 0; i < CIN; ++i) xv[i] = *(const float2*)(xb + (size_t)i * PLANE);  // 512B/wave

#pragma unroll
    for (int o = 0; o < COUT; ++o) {
        float bv = bias[o];
        float2 acc; acc.x = bv; acc.y = bv;
#pragma unroll
        for (int i = 0; i < CIN; ++i) {
            float w = Wm[o * CIN + i];          // thread-uniform -> scalar pipe
            acc.x += w * xv[i].x;
            acc.y += w * xv[i].y;
        }
        *(float2*)(fb + (size_t)o * PLANE) = acc;
    }
}

// ---------------- K1: pool x -> xpool_raw[b][i][25] (raw 52x52 bin sums) ----------------
// Grid 2048 = (b*32+i)*8 + strip ; 256 threads = 256 cols; strip = 32 rows.
__global__ __launch_bounds__(256) void pool_x_kernel(const float* __restrict__ x,
                                                     float* __restrict__ xpool) {
    int blk   = blockIdx.x;
    int s     = blk & 7;           // row strip 0..7
    int plane = blk >> 3;          // b*32+i, 0..255
    int t     = threadIdx.x;
    int gy0   = s * 32;

    const float* xp = x + (size_t)plane * PLANE + (size_t)gy0 * HW + t;
    float acc[KF] = {0.f, 0.f, 0.f, 0.f, 0.f};
#pragma unroll
    for (int r = 0; r < 32; ++r) {
        float v  = xp[(size_t)r * HW];
        int   gy = gy0 + r;
#pragma unroll
        for (int k = 0; k < KF; ++k) {            // row-bin membership (bins overlap by 1)
            const int sk = (k * HW) / KF;
            if (gy >= sk && gy < sk + BIN) acc[k] += v;
        }
    }

    __shared__ float lds[KF][HW + 1];
#pragma unroll
    for (int k = 0; k < KF; ++k) lds[k][t] = acc[k];
    __syncthreads();

    if (t < KF * KF) {                            // 25 workers: (row-bin kk, col-bin ll)
        int kk = t / KF, ll = t - kk * KF;
        int sl = (ll * HW) / KF;
        float ssum = 0.f;
#pragma unroll 4
        for (int w = 0; w < BIN; ++w) ssum += lds[kk][sl + w];
        atomicAdd(&xpool[plane * 25 + t], ssum);  // 2048*25 atomics total - negligible
    }
}

// ---------------- K2: depthwise 5x5, 16-row x 256-col strips, register sliding window ----
// 16-row strips: LDS 21KB -> up to 7 blocks/CU, staging overlaps compute across blocks.
// filt from xpool_raw in prologue (linearity of pooling).
#define RS 16      // output rows per strip
#define LROW 264   // LDS row stride (floats); interior col x at [lr*LROW + 4 + x]
__global__ __launch_bounds__(256, 6) void dwconv_kernel(const float* __restrict__ feat,
                                                        const float* __restrict__ xpool,
                                                        const float* __restrict__ Wm,
                                                        const float* __restrict__ bias,
                                                        float* __restrict__ out) {
    int bo    = blockIdx.y;            // 0..255  (b*32+o)
    int b     = bo >> 5;
    int o     = bo & 31;
    int strip = blockIdx.x;            // 0..15
    int gy0   = strip * RS;
    int t     = threadIdx.x;

    __shared__ __align__(16) float s[(RS + 4) * LROW];
    __shared__ float sfilt[25];

    // filt[k][l] = (sum_i W[o,i]*xpool_raw[b,i,k,l] + 2704*bias[o]) / 2704
    if (t < 25) {
        float acc = bias[o] * 2704.0f;
        const float* xp = xpool + (size_t)b * CIN * 25 + t;
#pragma unroll
        for (int i = 0; i < CIN; ++i) acc += Wm[o * CIN + i] * xp[i * 25];
        sfilt[t] = acc * (1.0f / 2704.0f);
    }
    // zero the 2-col pads (LDS idx 2,3 and 260,261) on each of RS+4 rows
    if (t < (RS + 4) * 4) {
        int lr = t >> 2, e = t & 3;
        int ci = (e < 2) ? (2 + e) : (258 + e);
        s[lr * LROW + ci] = 0.f;
    }

    const float* fb = feat + (size_t)bo * PLANE;
#pragma unroll
    for (int j = 0; j < 5; ++j) {          // (RS+4) rows x 64 float4 = 1280 / 256 threads
        int idx = t + 256 * j;
        int lr  = idx >> 6;
        int cx  = (idx & 63) * 4;
        int gy  = gy0 - 2 + lr;
        float4 v = {0.f, 0.f, 0.f, 0.f};
        if ((unsigned)gy < (unsigned)HW) v = *(const float4*)(fb + (size_t)gy * HW + cx);
        *(float4*)(&s[lr * LROW + 4 + cx]) = v;
    }
    __syncthreads();

    float fw[25];
#pragma unroll
    for (int j = 0; j < 25; ++j) fw[j] = sfilt[j];   // LDS broadcast once

    int c = t;   // output column
    float w0[5], w1[5], w2[5], w3[5], w4[5];
#pragma unroll
    for (int j = 0; j < 5; ++j) {
        w0[j] = s[0 * LROW + 2 + c + j];
        w1[j] = s[1 * LROW + 2 + c + j];
        w2[j] = s[2 * LROW + 2 + c + j];
        w3[j] = s[3 * LROW + 2 + c + j];
    }
    float* ob = out + (size_t)bo * PLANE + (size_t)gy0 * HW + c;
#pragma unroll
    for (int r = 0; r < RS; ++r) {
#pragma unroll
        for (int j = 0; j < 5; ++j) w4[j] = s[(r + 4) * LROW + 2 + c + j];
        float acc = 0.f;
#pragma unroll
        for (int j = 0; j < 5; ++j) {
            acc += fw[0 * 5 + j] * w0[j];
            acc += fw[1 * 5 + j] * w1[j];
            acc += fw[2 * 5 + j] * w2[j];
            acc += fw[3 * 5 + j] * w3[j];
            acc += fw[4 * 5 + j] * w4[j];
        }
        ob[(size_t)r * HW] = acc;
#pragma unroll
        for (int j = 0; j < 5; ++j) {      // renamed away under full unroll
            w0[j] = w1[j]; w1[j] = w2[j]; w2[j] = w3[j]; w3[j] = w4[j];
        }
    }
}

extern "C" void kernel_launch(void* const* d_in, const int* in_sizes, int n_in,
                              void* d_out, int out_size, void* d_ws, size_t ws_size,
                              hipStream_t stream) {
    const float* x      = (const float*)d_in[0];
    const float* conv_w = (const float*)d_in[1];
    const float* conv_b = (const float*)d_in[2];
    float* out = (float*)d_out;

    float* feat  = (float*)d_ws;                           // 64 MiB
    float* xpool = feat + (size_t)BATCH * COUT * PLANE;    // 8*32*25 floats (raw x bin sums)

    hipMemsetAsync(xpool, 0, BATCH * CIN * 25 * sizeof(float), stream);
    conv_kernel<<<dim3(1024), dim3(256), 0, stream>>>(x, conv_w, conv_b, feat);
    pool_x_kernel<<<dim3(2048), dim3(256), 0, stream>>>(x, xpool);
    dwconv_kernel<<<dim3(HW / RS, BATCH * COUT), dim3(256), 0, stream>>>(feat, xpool, conv_w, conv_b, out);
}